// Round 1
// baseline (380.206 us; speedup 1.0000x reference)
//
#include <hip/hip_runtime.h>
#include <math.h>

#define Bsz 64
#define Tn 1000
#define QD 1024
#define MD 512
#define AD 128
#define NF 32
#define KS 31
#define PADc 15

#define TT 64          // t-tile per block in energies kernel
#define AS_STRIDE 72   // 64 + 8 pad: keeps 16B alignment, breaks bank aliasing

// ---------------------------------------------------------------------------
// Kernel A1: qsum[b][a] = query[b]·Wq[a] + bq[a] + bm[a] + sum_f conv_b[f]*Wloc[a,f]
// ---------------------------------------------------------------------------
__global__ __launch_bounds__(128)
void k_qsum(const float* __restrict__ query, const float* __restrict__ Wq,
            const float* __restrict__ bq, const float* __restrict__ bm,
            const float* __restrict__ conv_b, const float* __restrict__ Wloc,
            float* __restrict__ qsum) {
    int b = blockIdx.x;
    int a = threadIdx.x; // 0..127
    __shared__ float qs[QD];
    for (int i = threadIdx.x; i < QD; i += 128) qs[i] = query[b * QD + i];
    __syncthreads();
    const float4* Wq4 = (const float4*)(Wq + a * QD);
    const float4* qs4 = (const float4*)qs;
    float acc = 0.f;
    for (int i = 0; i < QD / 4; ++i) {
        float4 w = Wq4[i];
        float4 q = qs4[i];
        acc += w.x * q.x + w.y * q.y + w.z * q.z + w.w * q.w;
    }
    float b2 = 0.f;
    for (int f = 0; f < NF; ++f) b2 += conv_b[f] * Wloc[a * NF + f];
    qsum[b * AD + a] = acc + bq[a] + bm[a] + b2;
}

// ---------------------------------------------------------------------------
// Kernel A2: W2t[k][a] = sum_f conv_w[f,0,k] * Wloc[a,f]   (stored [32][128], row 31 = 0)
// ---------------------------------------------------------------------------
__global__ __launch_bounds__(128)
void k_w2(const float* __restrict__ conv_w, const float* __restrict__ Wloc,
          float* __restrict__ W2t) {
    int a = threadIdx.x; // 0..127
    for (int k = 0; k < KS; ++k) {
        float s = 0.f;
        for (int f = 0; f < NF; ++f) s += conv_w[f * KS + k] * Wloc[a * NF + f];
        W2t[k * AD + a] = s;
    }
    W2t[KS * AD + a] = 0.f; // pad row so the loc chunk is a clean 32-deep K-chunk
}

// ---------------------------------------------------------------------------
// Kernel B: fused energies.
//   energies[b,t] = bv + sum_a Wv[a] * tanh( key[b,t,a] + loc[b,t,a] + qsum[b,a] )
//   key = memory @ Wm^T  handled as 16 K-chunks of 32;
//   loc = Toeplitz(awc) @ W2t handled as a 17th K-chunk.
// Block: 256 threads, tile 64 t x 128 a, each thread 8x4 outputs.
// ---------------------------------------------------------------------------
__global__ __launch_bounds__(256)
void k_energies(const float* __restrict__ mem, const float* __restrict__ awc,
                const float* __restrict__ Wm, const float* __restrict__ Wv,
                const float* __restrict__ bv, const float* __restrict__ qsum,
                const float* __restrict__ W2t, float* __restrict__ energies) {
    __shared__ float As[32 * AS_STRIDE]; // [kk][tt]
    __shared__ float Bs[32 * AD];        // [kk][aa]

    int b  = blockIdx.y;
    int t0 = blockIdx.x * TT;
    int tid = threadIdx.x;
    int tx = tid & 31;  // a-group: a = tx*4 + i
    int ty = tid >> 5;  // t-group: t = t0 + ty*8 + j

    float acc[8][4];
#pragma unroll
    for (int j = 0; j < 8; ++j)
#pragma unroll
        for (int i = 0; i < 4; ++i) acc[j][i] = 0.f;

    int ltt  = tid >> 2;  // 0..63  (A-tile row loaded by this thread)
    int kseg = tid & 3;   // 0..3   (8 consecutive k each)
    int laa  = tid >> 1;  // 0..127 (B-tile column loaded by this thread)
    int half = tid & 1;   // 0..1   (16 k each)

    for (int c = 0; c < 17; ++c) {
        if (c < 16) {
            int m0 = c * 32;
            // --- stage A tile (memory) transposed: As[kk][tt] ---
            int t = t0 + ltt;
            float4 v0 = make_float4(0.f, 0.f, 0.f, 0.f);
            float4 v1 = v0;
            if (t < Tn) {
                const float4* src =
                    (const float4*)(mem + (size_t)(b * Tn + t) * MD + m0 + kseg * 8);
                v0 = src[0];
                v1 = src[1];
            }
            As[(kseg * 8 + 0) * AS_STRIDE + ltt] = v0.x;
            As[(kseg * 8 + 1) * AS_STRIDE + ltt] = v0.y;
            As[(kseg * 8 + 2) * AS_STRIDE + ltt] = v0.z;
            As[(kseg * 8 + 3) * AS_STRIDE + ltt] = v0.w;
            As[(kseg * 8 + 4) * AS_STRIDE + ltt] = v1.x;
            As[(kseg * 8 + 5) * AS_STRIDE + ltt] = v1.y;
            As[(kseg * 8 + 6) * AS_STRIDE + ltt] = v1.z;
            As[(kseg * 8 + 7) * AS_STRIDE + ltt] = v1.w;
            // --- stage B tile (Wm) transposed: Bs[kk][aa] ---
            const float4* wsrc = (const float4*)(Wm + laa * MD + m0 + half * 16);
#pragma unroll
            for (int j4 = 0; j4 < 4; ++j4) {
                float4 w = wsrc[j4];
                int kk = half * 16 + j4 * 4;
                Bs[(kk + 0) * AD + laa] = w.x;
                Bs[(kk + 1) * AD + laa] = w.y;
                Bs[(kk + 2) * AD + laa] = w.z;
                Bs[(kk + 3) * AD + laa] = w.w;
            }
        } else {
            // --- location chunk: As[kk][tt] = awc[b, t0+tt+kk-15], Bs = W2t ---
            int t = t0 + ltt;
#pragma unroll
            for (int j = 0; j < 8; ++j) {
                int kk = kseg * 8 + j;
                int ts = t + kk - PADc;
                float v = 0.f;
                if (kk < KS && ts >= 0 && ts < Tn) v = awc[b * Tn + ts];
                As[kk * AS_STRIDE + ltt] = v;
            }
            const float4* s4 = (const float4*)W2t;
            float4* d4 = (float4*)Bs;
#pragma unroll
            for (int j4 = 0; j4 < 4; ++j4) d4[tid * 4 + j4] = s4[tid * 4 + j4];
        }
        __syncthreads();

#pragma unroll
        for (int kk = 0; kk < 32; ++kk) {
            const float* arow = &As[kk * AS_STRIDE + ty * 8];
            float4 a0 = *(const float4*)(arow);
            float4 a1 = *(const float4*)(arow + 4);
            float4 bb = *(const float4*)(&Bs[kk * AD + tx * 4]);
            float av[8] = {a0.x, a0.y, a0.z, a0.w, a1.x, a1.y, a1.z, a1.w};
            float bvv[4] = {bb.x, bb.y, bb.z, bb.w};
#pragma unroll
            for (int j = 0; j < 8; ++j)
#pragma unroll
                for (int i = 0; i < 4; ++i) acc[j][i] += av[j] * bvv[i];
        }
        __syncthreads();
    }

    // --- epilogue: tanh, dot with Wv, reduce over the 32 a-lanes ---
    float qs[4], wv[4];
#pragma unroll
    for (int i = 0; i < 4; ++i) {
        qs[i] = qsum[b * AD + tx * 4 + i];
        wv[i] = Wv[tx * 4 + i];
    }
    float bv0 = bv[0];
#pragma unroll
    for (int j = 0; j < 8; ++j) {
        float v = 0.f;
#pragma unroll
        for (int i = 0; i < 4; ++i) v += wv[i] * tanhf(acc[j][i] + qs[i]);
#pragma unroll
        for (int m2 = 1; m2 < 32; m2 <<= 1) v += __shfl_xor(v, m2, 64);
        if (tx == 0) {
            int t = t0 + ty * 8 + j;
            if (t < Tn) energies[b * Tn + t] = v + bv0;
        }
    }
}

// ---------------------------------------------------------------------------
// Kernel C: masked softmax over T per batch row; writes attention weights.
// ---------------------------------------------------------------------------
__global__ __launch_bounds__(256)
void k_softmax(const float* __restrict__ energies, const unsigned char* __restrict__ mask,
               float* __restrict__ wout) {
    int b = blockIdx.x;
    int tid = threadIdx.x;
    __shared__ float red[256];

    float e[4];
    float lmax = -1e30f;
#pragma unroll
    for (int i = 0; i < 4; ++i) {
        int t = tid + i * 256;
        float v = -1e30f;
        if (t < Tn) {
            v = energies[b * Tn + t];
            if (mask[b * Tn + t]) v = -1e30f; // -inf equivalent under softmax
        }
        e[i] = v;
        lmax = fmaxf(lmax, v);
    }
    red[tid] = lmax;
    __syncthreads();
    for (int s = 128; s > 0; s >>= 1) {
        if (tid < s) red[tid] = fmaxf(red[tid], red[tid + s]);
        __syncthreads();
    }
    float smax = red[0];
    __syncthreads();

    float ex[4];
    float lsum = 0.f;
#pragma unroll
    for (int i = 0; i < 4; ++i) {
        ex[i] = expf(e[i] - smax); // t>=Tn lanes give exp(-huge)=0
        lsum += ex[i];
    }
    red[tid] = lsum;
    __syncthreads();
    for (int s = 128; s > 0; s >>= 1) {
        if (tid < s) red[tid] += red[tid + s];
        __syncthreads();
    }
    float inv = 1.f / red[0];
#pragma unroll
    for (int i = 0; i < 4; ++i) {
        int t = tid + i * 256;
        if (t < Tn) wout[b * Tn + t] = ex[i] * inv;
    }
}

// ---------------------------------------------------------------------------
// Kernel D: context[b,m] = sum_t w[b,t] * memory[b,t,m]
// grid (8 t-chunks, 64 b); fp32 atomics (8-way per output, well within tolerance).
// ---------------------------------------------------------------------------
__global__ __launch_bounds__(256)
void k_context(const float* __restrict__ mem, const float* __restrict__ w,
               float* __restrict__ ctx) {
    int tc = blockIdx.x;
    int b  = blockIdx.y;
    int tid = threadIdx.x;
    __shared__ float ws[125];
    int tstart = tc * 125;
    if (tid < 125) ws[tid] = w[b * Tn + tstart + tid];
    __syncthreads();
    const float* mb = mem + (size_t)b * Tn * MD;
    float a0 = 0.f, a1 = 0.f;
    int m0 = tid, m1 = tid + 256;
    for (int i = 0; i < 125; ++i) {
        float wv = ws[i];
        const float* row = mb + (size_t)(tstart + i) * MD;
        a0 += wv * row[m0];
        a1 += wv * row[m1];
    }
    atomicAdd(&ctx[b * MD + m0], a0);
    atomicAdd(&ctx[b * MD + m1], a1);
}

// ---------------------------------------------------------------------------
extern "C" void kernel_launch(void* const* d_in, const int* in_sizes, int n_in,
                              void* d_out, int out_size, void* d_ws, size_t ws_size,
                              hipStream_t stream) {
    const float* query  = (const float*)d_in[0];
    const float* memory = (const float*)d_in[1];
    const float* awc    = (const float*)d_in[2];
    const unsigned char* mask = (const unsigned char*)d_in[3];
    const float* Wq     = (const float*)d_in[4];
    const float* bq     = (const float*)d_in[5];
    const float* Wm     = (const float*)d_in[6];
    const float* bm     = (const float*)d_in[7];
    const float* Wv     = (const float*)d_in[8];
    const float* bv     = (const float*)d_in[9];
    const float* conv_w = (const float*)d_in[10];
    const float* conv_b = (const float*)d_in[11];
    const float* Wloc   = (const float*)d_in[12];

    float* out  = (float*)d_out;
    float* ctx  = out;            // [64,512]
    float* wout = out + Bsz * MD; // [64,1000]

    float* ws    = (float*)d_ws;
    float* qsum  = ws;            // 64*128   = 8192 floats
    float* W2t   = ws + 8192;     // 32*128   = 4096 floats
    float* energ = ws + 12288;    // 64*1000  = 64000 floats

    hipMemsetAsync(ctx, 0, Bsz * MD * sizeof(float), stream);
    k_qsum<<<dim3(Bsz), dim3(128), 0, stream>>>(query, Wq, bq, bm, conv_b, Wloc, qsum);
    k_w2<<<dim3(1), dim3(128), 0, stream>>>(conv_w, Wloc, W2t);
    k_energies<<<dim3((Tn + TT - 1) / TT, Bsz), dim3(256), 0, stream>>>(
        memory, awc, Wm, Wv, bv, qsum, W2t, energ);
    k_softmax<<<dim3(Bsz), dim3(256), 0, stream>>>(energ, mask, wout);
    k_context<<<dim3(8, Bsz), dim3(256), 0, stream>>>(memory, wout, ctx);
}

// Round 2
// 312.175 us; speedup vs baseline: 1.2179x; 1.2179x over previous
//
#include <hip/hip_runtime.h>
#include <math.h>

#define Bsz 64
#define Tn 1000
#define QD 1024
#define MD 512
#define AD 128
#define NF 32
#define KS 31
#define PADc 15

#define TT 64  // t-tile per block in energies kernel

typedef __attribute__((ext_vector_type(8))) short bf16x8;
typedef __attribute__((ext_vector_type(4))) float f32x4;

static __device__ __forceinline__ short f2bf(float x) {
    unsigned u = __float_as_uint(x);
    unsigned r = (u + 0x7fffu + ((u >> 16) & 1u)) >> 16;  // round-to-nearest-even
    return (short)r;
}

// ---------------------------------------------------------------------------
// Kernel A1: qsum[b][a] = query[b]·Wq[a] + bq[a] + bm[a] + sum_f conv_b[f]*Wloc[a,f]
// 256 threads: 2 threads per a-row, each half the 1024-dot.
// ---------------------------------------------------------------------------
__global__ __launch_bounds__(256)
void k_qsum(const float* __restrict__ query, const float* __restrict__ Wq,
            const float* __restrict__ bq, const float* __restrict__ bm,
            const float* __restrict__ conv_b, const float* __restrict__ Wloc,
            float* __restrict__ qsum) {
    int b = blockIdx.x;
    int a = threadIdx.x & 127;
    int half = threadIdx.x >> 7;
    __shared__ float qs[QD];
    __shared__ float red[256];
    for (int i = threadIdx.x; i < QD; i += 256) qs[i] = query[b * QD + i];
    __syncthreads();
    const float4* Wq4 = (const float4*)(Wq + a * QD + half * (QD / 2));
    const float4* qs4 = (const float4*)(qs + half * (QD / 2));
    float acc = 0.f;
#pragma unroll 4
    for (int i = 0; i < QD / 8; ++i) {
        float4 w = Wq4[i];
        float4 q = qs4[i];
        acc += w.x * q.x + w.y * q.y + w.z * q.z + w.w * q.w;
    }
    red[threadIdx.x] = acc;
    __syncthreads();
    if (half == 0) {
        float b2 = 0.f;
        for (int f = 0; f < NF; ++f) b2 += conv_b[f] * Wloc[a * NF + f];
        qsum[b * AD + a] = red[a] + red[a + 128] + bq[a] + bm[a] + b2;
    }
}

// ---------------------------------------------------------------------------
// Kernel A2 (prep): blocks 0..63 cast Wm -> WmB (bf16, [128][512] row-major);
// block 64 computes W2B[a][k] = sum_f conv_w[f,0,k]*Wloc[a,f]  (bf16, [128][32], k=31 pad=0)
// ---------------------------------------------------------------------------
__global__ __launch_bounds__(256)
void k_prep(const float* __restrict__ Wm, const float* __restrict__ conv_w,
            const float* __restrict__ Wloc, short* __restrict__ WmB,
            short* __restrict__ W2B) {
    if (blockIdx.x < 64) {
        int base = blockIdx.x * 1024 + threadIdx.x * 4;
        float4 v = *(const float4*)(Wm + base);
        short4 o;
        o.x = f2bf(v.x); o.y = f2bf(v.y); o.z = f2bf(v.z); o.w = f2bf(v.w);
        *(short4*)(WmB + base) = o;
    } else {
        if (threadIdx.x < 128) {
            int a = threadIdx.x;
            for (int k = 0; k < KS; ++k) {
                float s = 0.f;
                for (int f = 0; f < NF; ++f) s += conv_w[f * KS + k] * Wloc[a * NF + f];
                W2B[a * 32 + k] = f2bf(s);
            }
            W2B[a * 32 + KS] = 0;
        }
    }
}

// ---------------------------------------------------------------------------
// Kernel B: fused energies via bf16 MFMA.
//   energies[b,t] = bv + sum_a Wv[a] * tanh( key + loc + qsum )
//   key = mem @ Wm^T as 16 K-chunks of 32 (A staged fp32->bf16 in LDS,
//   B-frags read direct from L1/L2-resident WmB); loc = Toeplitz(awc) @ W2B
//   as a 17th chunk. Block: 256 threads = 4 waves; wave w computes
//   t-rows [t0+16w, t0+16w+16) x all 128 a (8 MFMA tiles).
// ---------------------------------------------------------------------------
__global__ __launch_bounds__(256)
void k_energies(const float* __restrict__ mem, const float* __restrict__ awc,
                const short* __restrict__ WmB, const short* __restrict__ W2B,
                const float* __restrict__ Wv, const float* __restrict__ bv,
                const float* __restrict__ qsum, float* __restrict__ energies) {
    __shared__ short As[TT * 32];  // [t][k] bf16, row = 64B — conflict-free b128 pattern

    int b = blockIdx.y;
    int t0 = blockIdx.x * TT;
    int tid = threadIdx.x;
    int wid = tid >> 6;   // wave 0..3 -> t-rows t0+wid*16 ..
    int lane = tid & 63;
    int m16 = lane & 15;  // row-in-tile (A) / col-in-tile (B)
    int q = lane >> 4;    // 0..3 -> k-subgroup (frags) / row-subgroup (C/D)

    int lt = tid >> 2;         // 0..63: t-row staged by this thread
    int lk = (tid & 3) * 8;    // k offset 0/8/16/24

    f32x4 acc[8];
#pragma unroll
    for (int i = 0; i < 8; ++i) acc[i] = (f32x4){0.f, 0.f, 0.f, 0.f};

    for (int c = 0; c < 17; ++c) {
        // ---- stage A tile (bf16) ----
        int t = t0 + lt;
        bf16x8 pack;
        if (c < 16) {
            float4 v0 = make_float4(0.f, 0.f, 0.f, 0.f), v1 = v0;
            if (t < Tn) {
                const float4* src = (const float4*)(mem + (size_t)(b * Tn + t) * MD + c * 32 + lk);
                v0 = src[0];
                v1 = src[1];
            }
            pack[0] = f2bf(v0.x); pack[1] = f2bf(v0.y);
            pack[2] = f2bf(v0.z); pack[3] = f2bf(v0.w);
            pack[4] = f2bf(v1.x); pack[5] = f2bf(v1.y);
            pack[6] = f2bf(v1.z); pack[7] = f2bf(v1.w);
        } else {
#pragma unroll
            for (int j = 0; j < 8; ++j) {
                int kk = lk + j;
                int ts = t + kk - PADc;
                float v = 0.f;
                if (kk < KS && ts >= 0 && ts < Tn && t < Tn) v = awc[b * Tn + ts];
                pack[j] = f2bf(v);
            }
        }
        __syncthreads();  // protect As from previous iteration's readers
        *(bf16x8*)&As[lt * 32 + lk] = pack;
        __syncthreads();

        // ---- A fragment: A[m=lane&15][k=q*8+j] ----
        bf16x8 afrag = *(const bf16x8*)&As[(wid * 16 + m16) * 32 + q * 8];

        // ---- 8 MFMA tiles along a; B[k][n]: n=lane&15 holds 8 consecutive k ----
        if (c < 16) {
#pragma unroll
            for (int na = 0; na < 8; ++na) {
                bf16x8 bfrag = *(const bf16x8*)&WmB[(size_t)(na * 16 + m16) * MD + c * 32 + q * 8];
                acc[na] = __builtin_amdgcn_mfma_f32_16x16x32_bf16(afrag, bfrag, acc[na], 0, 0, 0);
            }
        } else {
#pragma unroll
            for (int na = 0; na < 8; ++na) {
                bf16x8 bfrag = *(const bf16x8*)&W2B[(na * 16 + m16) * 32 + q * 8];
                acc[na] = __builtin_amdgcn_mfma_f32_16x16x32_bf16(afrag, bfrag, acc[na], 0, 0, 0);
            }
        }
    }

    // ---- epilogue: tanh, dot Wv, reduce over the 16 a-lanes ----
    // C/D layout: col(a) = na*16 + m16, row(t) = wid*16 + q*4 + r
    float wvv[8], qsv[8];
#pragma unroll
    for (int na = 0; na < 8; ++na) {
        int a = na * 16 + m16;
        wvv[na] = Wv[a];
        qsv[na] = qsum[b * AD + a];
    }
    float bv0 = bv[0];
#pragma unroll
    for (int r = 0; r < 4; ++r) {
        float e = 0.f;
#pragma unroll
        for (int na = 0; na < 8; ++na) e += wvv[na] * tanhf(acc[na][r] + qsv[na]);
#pragma unroll
        for (int m2 = 1; m2 < 16; m2 <<= 1) e += __shfl_xor(e, m2, 64);
        if (m16 == 0) {
            int t = t0 + wid * 16 + q * 4 + r;
            if (t < Tn) energies[b * Tn + t] = e + bv0;
        }
    }
}

// ---------------------------------------------------------------------------
// Kernel C: masked softmax over T per batch row.
// ---------------------------------------------------------------------------
__global__ __launch_bounds__(256)
void k_softmax(const float* __restrict__ energies, const unsigned char* __restrict__ mask,
               float* __restrict__ wout) {
    int b = blockIdx.x;
    int tid = threadIdx.x;
    __shared__ float red[256];

    float e[4];
    float lmax = -1e30f;
#pragma unroll
    for (int i = 0; i < 4; ++i) {
        int t = tid + i * 256;
        float v = -1e30f;
        if (t < Tn) {
            v = energies[b * Tn + t];
            if (mask[b * Tn + t]) v = -1e30f;
        }
        e[i] = v;
        lmax = fmaxf(lmax, v);
    }
    red[tid] = lmax;
    __syncthreads();
    for (int s = 128; s > 0; s >>= 1) {
        if (tid < s) red[tid] = fmaxf(red[tid], red[tid + s]);
        __syncthreads();
    }
    float smax = red[0];
    __syncthreads();

    float ex[4];
    float lsum = 0.f;
#pragma unroll
    for (int i = 0; i < 4; ++i) {
        ex[i] = expf(e[i] - smax);
        lsum += ex[i];
    }
    red[tid] = lsum;
    __syncthreads();
    for (int s = 128; s > 0; s >>= 1) {
        if (tid < s) red[tid] += red[tid + s];
        __syncthreads();
    }
    float inv = 1.f / red[0];
#pragma unroll
    for (int i = 0; i < 4; ++i) {
        int t = tid + i * 256;
        if (t < Tn) wout[b * Tn + t] = ex[i] * inv;
    }
}

// ---------------------------------------------------------------------------
// Kernel D: context[b,m] = sum_t w[b,t] * memory[b,t,m]
// ---------------------------------------------------------------------------
__global__ __launch_bounds__(256)
void k_context(const float* __restrict__ mem, const float* __restrict__ w,
               float* __restrict__ ctx) {
    int tc = blockIdx.x;
    int b = blockIdx.y;
    int tid = threadIdx.x;
    __shared__ float ws[125];
    int tstart = tc * 125;
    if (tid < 125) ws[tid] = w[b * Tn + tstart + tid];
    __syncthreads();
    const float* mb = mem + (size_t)b * Tn * MD;
    float a0 = 0.f, a1 = 0.f;
    int m0 = tid, m1 = tid + 256;
    for (int i = 0; i < 125; ++i) {
        float wv = ws[i];
        const float* row = mb + (size_t)(tstart + i) * MD;
        a0 += wv * row[m0];
        a1 += wv * row[m1];
    }
    atomicAdd(&ctx[b * MD + m0], a0);
    atomicAdd(&ctx[b * MD + m1], a1);
}

// ---------------------------------------------------------------------------
extern "C" void kernel_launch(void* const* d_in, const int* in_sizes, int n_in,
                              void* d_out, int out_size, void* d_ws, size_t ws_size,
                              hipStream_t stream) {
    const float* query  = (const float*)d_in[0];
    const float* memory = (const float*)d_in[1];
    const float* awc    = (const float*)d_in[2];
    const unsigned char* mask = (const unsigned char*)d_in[3];
    const float* Wq     = (const float*)d_in[4];
    const float* bq     = (const float*)d_in[5];
    const float* Wm     = (const float*)d_in[6];
    const float* bm     = (const float*)d_in[7];
    const float* Wv     = (const float*)d_in[8];
    const float* bv     = (const float*)d_in[9];
    const float* conv_w = (const float*)d_in[10];
    const float* conv_b = (const float*)d_in[11];
    const float* Wloc   = (const float*)d_in[12];

    float* out = (float*)d_out;
    float* ctx = out;             // [64,512]
    float* wout = out + Bsz * MD; // [64,1000]

    float* ws = (float*)d_ws;
    float* qsum  = ws;             // 8192 f
    float* energ = ws + 8192;      // 64000 f  -> ends at 72192 f = 288768 B
    short* WmB = (short*)((char*)d_ws + 288768);  // 64K bf16 = 131072 B
    short* W2B = (short*)((char*)d_ws + 288768 + 131072);  // 4096 bf16

    hipMemsetAsync(ctx, 0, Bsz * MD * sizeof(float), stream);
    k_qsum<<<dim3(Bsz), dim3(256), 0, stream>>>(query, Wq, bq, bm, conv_b, Wloc, qsum);
    k_prep<<<dim3(65), dim3(256), 0, stream>>>(Wm, conv_w, Wloc, WmB, W2B);
    k_energies<<<dim3((Tn + TT - 1) / TT, Bsz), dim3(256), 0, stream>>>(
        memory, awc, WmB, W2B, Wv, bv, qsum, energ);
    k_softmax<<<dim3(Bsz), dim3(256), 0, stream>>>(energ, mask, wout);
    k_context<<<dim3(8, Bsz), dim3(256), 0, stream>>>(memory, wout, ctx);
}